// Round 3
// baseline (15569.157 us; speedup 1.0000x reference)
//
#include <hip/hip_runtime.h>
#include <math.h>

typedef _Float16 f16;
typedef f16 f16x2 __attribute__((ext_vector_type(2)));
typedef f16 f16x4 __attribute__((ext_vector_type(4)));
typedef f16 f16x8 __attribute__((ext_vector_type(8)));
typedef float f32x4 __attribute__((ext_vector_type(4)));

#define NB 128      // batch
#define TT 256      // time steps
#define DD 1024     // input dim
#define HH 1024     // hidden dim
#define PP 196      // spatial positions
#define K3 3072     // folded K = D + H + H
#define FOURH 4096
#define NBLK 256
#define NTHR 512
#define WROW 3078   // LDS row stride (f16): 1539 dw == 3 mod 8 -> <=3-way conflicts
#define LDS_BYTES (16 * WROW * 2 + 9216 * 4)
// bar layout: barA = bar[0..4095], barG = bar[4096..8191], pair flags after.
// Within a bar region: leaves at 64*i (i<16), root at 1024,
// fan-out generation lines at 1088 + 64*i (i<16)  [<=16 pollers per line].
#define BAR_U32 (8192 + 128 * 64)

#if __has_builtin(__builtin_amdgcn_fdot2)
#define FDOT2(a, b, c) __builtin_amdgcn_fdot2((a), (b), (c), false)
#else
#define FDOT2(a, b, c) \
  ((c) + (float)(a)[0] * (float)(b)[0] + (float)(a)[1] * (float)(b)[1])
#endif

// ---------------- P1: h0 = c0 = mean_p A[n][h][:]  ----------------
__global__ void k_h0(const float* __restrict__ A, float* __restrict__ c0,
                     f16* __restrict__ act_h0) {
  int idx = blockIdx.x * 256 + threadIdx.x;
  const float4* ap = (const float4*)(A + (size_t)idx * PP);
  float s = 0.f;
#pragma unroll
  for (int i = 0; i < PP / 4; ++i) { float4 v = ap[i]; s += v.x + v.y + v.z + v.w; }
  float m = s * (1.0f / PP);
  c0[idx] = m;
  act_h0[idx] = (f16)m;
}

// ---------------- P2: A[n][h][p] fp32 -> A2[n][p][h] fp16 ----------------
__global__ void k_At(const float* __restrict__ A, f16* __restrict__ A2) {
  __shared__ float tile[32][33];
  int p0 = blockIdx.x * 32, h0 = blockIdx.y * 32, n = blockIdx.z;
  for (int i = threadIdx.x; i < 1024; i += 256) {
    int r = i >> 5, c = i & 31;
    int p = p0 + c;
    float v = 0.f;
    if (p < PP) v = A[((size_t)n * HH + h0 + r) * PP + p];
    tile[r][c] = v;
  }
  __syncthreads();
  for (int i = threadIdx.x; i < 1024; i += 256) {
    int r = i >> 5, c = i & 31;
    int p = p0 + r;
    if (p < PP) A2[((size_t)n * PP + p) * HH + h0 + c] = (f16)tile[c][r];
  }
}

// ------ P3: Wt[j][k] fp16, col-major weights, k = [Wx;Wh;Wattn] ----------
__global__ void k_Wt(const float* __restrict__ Wx, const float* __restrict__ Wh,
                     const float* __restrict__ Wa, f16* __restrict__ Wt) {
  __shared__ float tile[32][33];
  int k0 = blockIdx.x * 32, j0 = blockIdx.y * 32;
  const float* src; int kb;
  if (k0 < 1024)      { src = Wx; kb = k0; }
  else if (k0 < 2048) { src = Wh; kb = k0 - 1024; }
  else                { src = Wa; kb = k0 - 2048; }
  for (int i = threadIdx.x; i < 1024; i += 256) {
    int r = i >> 5, c = i & 31;
    tile[r][c] = src[(size_t)(kb + r) * FOURH + j0 + c];
  }
  __syncthreads();
  for (int i = threadIdx.x; i < 1024; i += 256) {
    int r = i >> 5, c = i & 31;
    Wt[(size_t)(j0 + r) * K3 + k0 + c] = (f16)tile[c][r];
  }
}

// ---------------- P4: x fp32 -> fp16 ----------------
__global__ void k_xcvt(const float* __restrict__ x, f16* __restrict__ xh) {
  size_t i = (size_t)blockIdx.x * 256 + threadIdx.x;
  float4 v = ((const float4*)x)[i];
  f16x4 o; o[0] = (f16)v.x; o[1] = (f16)v.y; o[2] = (f16)v.z; o[3] = (f16)v.w;
  *(f16x4*)(xh + i * 4) = o;
}

// ------------- relaxed barrier primitives (no wbl2/inv on arrive) ------------
__device__ __forceinline__ void bar_arrive(unsigned* base, int bx) {
  asm volatile("s_waitcnt vmcnt(0)" ::: "memory");
  unsigned lv = __hip_atomic_fetch_add(base + (bx & 15) * 64, 1u,
                                       __ATOMIC_RELAXED, __HIP_MEMORY_SCOPE_AGENT);
  if ((lv & 15u) == 15u) {
    unsigned rv = __hip_atomic_fetch_add(base + 1024, 1u,
                                         __ATOMIC_RELAXED, __HIP_MEMORY_SCOPE_AGENT);
    if ((rv & 15u) == 15u) {
      unsigned g = (rv >> 4) + 1u;
#pragma unroll
      for (int i = 0; i < 16; ++i)
        __hip_atomic_store(base + 1088 + i * 64, g,
                           __ATOMIC_RELAXED, __HIP_MEMORY_SCOPE_AGENT);
    }
  }
}
__device__ __forceinline__ void bar_wait_acq(unsigned* base, int bx, unsigned target) {
  unsigned* line = base + 1088 + (bx & 15) * 64;
  while (__hip_atomic_load(line, __ATOMIC_RELAXED,
                           __HIP_MEMORY_SCOPE_AGENT) < target)
    __builtin_amdgcn_s_sleep(1);
  // acquire: single L2 invalidate so subsequent CACHED loads see coherent data
  (void)__hip_atomic_load(line, __ATOMIC_ACQUIRE, __HIP_MEMORY_SCOPE_AGENT);
}

__device__ __forceinline__ void coh_store_f16(f16* p, f16 v) {
  __hip_atomic_store((short*)p, __builtin_bit_cast(short, v),
                     __ATOMIC_RELAXED, __HIP_MEMORY_SCOPE_AGENT);
}
__device__ __forceinline__ void coh_store_f32(float* p, float v) {
  __hip_atomic_store(p, v, __ATOMIC_RELAXED, __HIP_MEMORY_SCOPE_AGENT);
}
__device__ __forceinline__ float coh_load_f32(const float* p) {
  return __hip_atomic_load(p, __ATOMIC_RELAXED, __HIP_MEMORY_SCOPE_AGENT);
}

// ---------------- persistent per-step kernel (cooperative) ----------------
// 256 blocks x 512 threads, 1 block/CU. A2 slice in registers; Wt slice in LDS.
// Pairing: partner = bx ^ 8 (same XCD under round-robin block->XCD mapping),
//   n = (bx & 7) | ((bx >> 4) << 3), hhalf = (bx >> 3) & 1.
// Per step: S -> pair-arrive -> G(x,h pre-compute) -> pair-wait -> A ->
//           global barA -> G(attn) + epilogue -> global barG.
__global__ __launch_bounds__(NTHR, 2) void k_steps(
    const f16* __restrict__ xh, const f16* __restrict__ A2,
    const f16* __restrict__ Wtg, const float* __restrict__ bias,
    const float* __restrict__ c0,
    f16* __restrict__ acth0, f16* __restrict__ acth1,
    f16* __restrict__ attnb, float* __restrict__ spart,
    float* __restrict__ out, unsigned* __restrict__ bar) {
  extern __shared__ char smem[];
  f16* wslab = (f16*)smem;                         // [16][WROW]
  float* uni   = (float*)(smem + 16 * WROW * 2);   // 9216 floats
  float* sc    = uni;                              // [208] own score partials
  float* wexp  = uni + 208;                        // [208] softmax weights
  float* srinv = uni + 416;
  float* red   = uni + 512;                        // [16][32][17] attn partials
  float* slabq = uni;                              // G: [4][128][18]

  int tid = threadIdx.x;
  int lane = tid & 63, wid = tid >> 6;
  int bx = blockIdx.x;
  unsigned* barA = bar;
  unsigned* barG = bar + 4096;

  // ---- S/A geometry (same-XCD pairing: partner differs in bit 3 only) ----
  int n = (bx & 7) | ((bx >> 4) << 3);
  int hhalf = (bx >> 3) & 1;
  int pbx = bx ^ 8;
  unsigned* pflag = bar + 8192 + n * 64;
  int hsub = lane & 31;
  int pg = wid * 2 + (lane >> 5);

  // ---- A2 slice into registers (resident forever) ----
  f16x8 areg0[13], areg1[13];
  {
    const f16* Ab = A2 + ((size_t)n * PP) * HH + hhalf * 512 + hsub * 16;
#pragma unroll
    for (int i = 0; i < 13; ++i) {
      int p = pg + 16 * i; if (p >= PP) p = pg;
      areg0[i] = *(const f16x8*)(Ab + (size_t)p * HH);
      areg1[i] = *(const f16x8*)(Ab + (size_t)p * HH + 8);
    }
  }

  // ---- Wt slice into LDS (resident forever) ----
#pragma unroll 1
  for (int c = 0; c < 16; ++c) {
    if (tid < 384) {
      int j = (c >> 2) * 1024 + bx * 4 + (c & 3);
      f16x8 v = *(const f16x8*)(Wtg + (size_t)j * K3 + tid * 8);
      *(f16x8*)(wslab + c * WROW + tid * 8) = v;
    }
  }

  // ---- G geometry ----
  int l15 = lane & 15, quad = lane >> 4;
  int mhalf = wid & 1, kq = wid >> 1;
  int rowbase = mhalf * 64 + l15;
  const f16* wlp = wslab + l15 * WROW + quad * 8;
  int gn = tid >> 2, gh = tid & 3;
  int hs4 = bx * 4;
  float creg = c0[gn * HH + hs4 + gh];
  float b_i = bias[hs4 + gh], b_f = bias[1024 + hs4 + gh];
  float b_o = bias[2048 + hs4 + gh], b_g = bias[3072 + hs4 + gh];

  for (int t = 0; t < TT; ++t) {
    const f16* hcur = (t & 1) ? acth1 : acth0;
    f16* hnxt = (t & 1) ? acth0 : acth1;
    unsigned tgt = (unsigned)(t + 1);

    // ============ phase S: partial scores over this block's 512 h ============
    {
      const f16x8* hp = (const f16x8*)(hcur + (size_t)n * HH + hhalf * 512 + hsub * 16);
      f16x8 hv0 = hp[0], hv1 = hp[1];
      f16x2 h2[8];
#pragma unroll
      for (int j = 0; j < 4; ++j) {
        h2[j]     = *(((const f16x2*)&hv0) + j);
        h2[4 + j] = *(((const f16x2*)&hv1) + j);
      }
#pragma unroll
      for (int i = 0; i < 13; ++i) {
        float s = 0.f;
#pragma unroll
        for (int j = 0; j < 4; ++j) {
          s = FDOT2(*(((const f16x2*)&areg0[i]) + j), h2[j], s);
          s = FDOT2(*(((const f16x2*)&areg1[i]) + j), h2[4 + j], s);
        }
        s += __shfl_xor(s, 1, 64);
        s += __shfl_xor(s, 2, 64);
        s += __shfl_xor(s, 4, 64);
        s += __shfl_xor(s, 8, 64);
        s += __shfl_xor(s, 16, 64);
        int p = pg + 16 * i;
        if (hsub == 0 && p < PP) {
          sc[p] = s;
          coh_store_f32(spart + bx * 256 + p, s);
        }
      }
    }
    __syncthreads();                       // drains coherent spart stores
    if (tid == 0)
      __hip_atomic_fetch_add(pflag, 1u, __ATOMIC_RELAXED, __HIP_MEMORY_SCOPE_AGENT);

    // ============ phase Gxh: x-part + h-part of the gates GEMM (no attn dep) =
    f32x4 acc4[4];
#pragma unroll
    for (int i = 0; i < 4; ++i)
#pragma unroll
      for (int e = 0; e < 4; ++e) acc4[i][e] = 0.f;

    auto seg = [&](const f16* base, size_t rstride, int kgbase, int nks) {
#pragma unroll 4
      for (int ks = 0; ks < nks; ++ks) {
        const f16* ap = base + ks * 32 + quad * 8;
        f16x8 b = *(const f16x8*)(wlp + kgbase + ks * 32);
        f16x8 a0 = *(const f16x8*)(ap + (size_t)(rowbase)      * rstride);
        f16x8 a1 = *(const f16x8*)(ap + (size_t)(rowbase + 16) * rstride);
        f16x8 a2 = *(const f16x8*)(ap + (size_t)(rowbase + 32) * rstride);
        f16x8 a3 = *(const f16x8*)(ap + (size_t)(rowbase + 48) * rstride);
        acc4[0] = __builtin_amdgcn_mfma_f32_16x16x32_f16(a0, b, acc4[0], 0, 0, 0);
        acc4[1] = __builtin_amdgcn_mfma_f32_16x16x32_f16(a1, b, acc4[1], 0, 0, 0);
        acc4[2] = __builtin_amdgcn_mfma_f32_16x16x32_f16(a2, b, acc4[2], 0, 0, 0);
        acc4[3] = __builtin_amdgcn_mfma_f32_16x16x32_f16(a3, b, acc4[3], 0, 0, 0);
      }
    };
    {
      const f16* xrow = xh + (size_t)t * DD;
      if (kq == 0)      seg(xrow,        (size_t)TT * DD, 0,    16);
      else if (kq == 1) seg(xrow + 512,  (size_t)TT * DD, 512,  16);
      else if (kq == 2) seg(hcur,        HH,              1024, 16);
      else              seg(hcur + 512,  HH,              1536, 16);
    }

    // ============ pair-wait, then phase A (softmax + attn from registers) ====
    if (tid == 0) {
      while (__hip_atomic_load(pflag, __ATOMIC_RELAXED, __HIP_MEMORY_SCOPE_AGENT)
             < 2u * tgt)
        __builtin_amdgcn_s_sleep(1);
    }
    __syncthreads();
    {
      if (wid == 0) {
        const float* pp = spart + (size_t)pbx * 256;
        float s0 = (sc[lane]       + coh_load_f32(pp + lane))       * 0.03125f;
        float s1 = (sc[64 + lane]  + coh_load_f32(pp + 64 + lane))  * 0.03125f;
        float s2 = (sc[128 + lane] + coh_load_f32(pp + 128 + lane)) * 0.03125f;
        float s3 = (lane < 4) ? (sc[192 + lane] + coh_load_f32(pp + 192 + lane)) * 0.03125f
                              : -1e30f;
        float mx = fmaxf(fmaxf(s0, s1), fmaxf(s2, s3));
#pragma unroll
        for (int off = 32; off > 0; off >>= 1) mx = fmaxf(mx, __shfl_xor(mx, off, 64));
        float e0 = __expf(s0 - mx), e1 = __expf(s1 - mx), e2 = __expf(s2 - mx);
        float e3 = (lane < 4) ? __expf(s3 - mx) : 0.f;
        float ssum = e0 + e1 + e2 + e3;
#pragma unroll
        for (int off = 32; off > 0; off >>= 1) ssum += __shfl_xor(ssum, off, 64);
        wexp[lane] = e0; wexp[64 + lane] = e1; wexp[128 + lane] = e2;
        if (lane < 4)  wexp[192 + lane] = e3;
        if (lane < 12) wexp[196 + lane] = 0.f;
        if (lane == 0) *srinv = 1.f / ssum;
      }
      __syncthreads();
      float acc[16];
#pragma unroll
      for (int e = 0; e < 16; ++e) acc[e] = 0.f;
#pragma unroll
      for (int i = 0; i < 13; ++i) {
        float wgt = wexp[pg + 16 * i];
#pragma unroll
        for (int e = 0; e < 8; ++e) {
          acc[e]     += wgt * (float)areg0[i][e];
          acc[8 + e] += wgt * (float)areg1[i][e];
        }
      }
#pragma unroll
      for (int e = 0; e < 16; ++e) red[pg * 544 + hsub * 17 + e] = acc[e];
      __syncthreads();
      float s = 0.f;
      int ra = (tid >> 4) * 17 + (tid & 15);
#pragma unroll
      for (int g = 0; g < 16; ++g) s += red[g * 544 + ra];
      coh_store_f16(attnb + (size_t)n * HH + hhalf * 512 + tid,
                    (f16)(s * (*srinv)));
    }
    __syncthreads();                       // drains coherent attnb stores
    if (tid == 0) { bar_arrive(barA, bx); bar_wait_acq(barA, bx, tgt); }
    __syncthreads();

    // ============ phase Gattn: attn-part of GEMM + LSTM epilogue =============
    seg(attnb + kq * 256, HH, 2048 + kq * 256, 8);

#pragma unroll
    for (int mt = 0; mt < 4; ++mt)
#pragma unroll
      for (int jr = 0; jr < 4; ++jr)
        slabq[kq * 2304 + (mhalf * 64 + mt * 16 + quad * 4 + jr) * 18 + l15] =
            acc4[mt][jr];
    __syncthreads();
    {
      float ai = b_i, af = b_f, ao = b_o, ag = b_g;
#pragma unroll
      for (int q = 0; q < 4; ++q) {
        const float* sl = slabq + q * 2304 + gn * 18;
        ai += sl[gh]; af += sl[4 + gh]; ao += sl[8 + gh]; ag += sl[12 + gh];
      }
      float ig = 1.f / (1.f + __expf(-ai));
      float fg = 1.f / (1.f + __expf(-af));
      float og = 1.f / (1.f + __expf(-ao));
      float gg = tanhf(ag);
      creg = fg * creg + ig * gg;
      float hn = og * tanhf(creg);
      __builtin_nontemporal_store(hn, &out[((size_t)gn * TT + t) * HH + hs4 + gh]);
      coh_store_f16(hnxt + gn * HH + hs4 + gh, (f16)hn);
    }
    __syncthreads();                       // drains coherent acth stores
    if (tid == 0) { bar_arrive(barG, bx); bar_wait_acq(barG, bx, tgt); }
    __syncthreads();
  }
}

extern "C" void kernel_launch(void* const* d_in, const int* in_sizes, int n_in,
                              void* d_out, int out_size, void* d_ws, size_t ws_size,
                              hipStream_t stream) {
  const float* x  = (const float*)d_in[0];
  const float* A  = (const float*)d_in[1];
  const float* Wx = (const float*)d_in[2];
  const float* Wh = (const float*)d_in[3];
  const float* Wa = (const float*)d_in[4];
  const float* b  = (const float*)d_in[5];
  float* out = (float*)d_out;

  char* ws = (char*)d_ws;
  f16* A2 = (f16*)ws;          ws += (size_t)NB * PP * HH * 2;
  f16* Wt = (f16*)ws;          ws += (size_t)FOURH * K3 * 2;
  f16* xh = (f16*)ws;          ws += (size_t)NB * TT * DD * 2;
  f16* acth0 = (f16*)ws;       ws += (size_t)NB * HH * 2;
  f16* acth1 = (f16*)ws;       ws += (size_t)NB * HH * 2;
  f16* attnb = (f16*)ws;       ws += (size_t)NB * HH * 2;
  float* c0 = (float*)ws;      ws += (size_t)NB * HH * 4;
  float* spart = (float*)ws;   ws += (size_t)NBLK * 256 * 4;
  unsigned* bar = (unsigned*)ws; ws += (size_t)BAR_U32 * 4;

  static int attr_set = 0;
  if (!attr_set) {
    hipFuncSetAttribute((const void*)k_steps,
                        hipFuncAttributeMaxDynamicSharedMemorySize, LDS_BYTES);
    attr_set = 1;
  }

  hipMemsetAsync(bar, 0, BAR_U32 * 4, stream);
  k_h0<<<512, 256, 0, stream>>>(A, c0, acth0);
  k_At<<<dim3(7, 32, NB), 256, 0, stream>>>(A, A2);
  k_Wt<<<dim3(96, 128), 256, 0, stream>>>(Wx, Wh, Wa, Wt);
  k_xcvt<<<32768, 256, 0, stream>>>(x, xh);

  void* args[] = { (void*)&xh, (void*)&A2, (void*)&Wt, (void*)&b, (void*)&c0,
                   (void*)&acth0, (void*)&acth1, (void*)&attnb, (void*)&spart,
                   (void*)&out, (void*)&bar };
  hipLaunchCooperativeKernel((const void*)k_steps, dim3(NBLK), dim3(NTHR),
                             args, LDS_BYTES, stream);
}

// Round 4
// 12671.797 us; speedup vs baseline: 1.2286x; 1.2286x over previous
//
#include <hip/hip_runtime.h>
#include <math.h>

typedef _Float16 f16;
typedef f16 f16x4 __attribute__((ext_vector_type(4)));
typedef f16 f16x8 __attribute__((ext_vector_type(8)));
typedef float f32x4 __attribute__((ext_vector_type(4)));

#define NB 128      // batch
#define TT 256      // time steps
#define DD 1024     // input dim
#define HH 1024     // hidden dim
#define PP 196      // spatial positions
#define K3 3072     // folded K = D + H + H
#define FOURH 4096
#define NBLK 256
#define NTHR 512
#define WROW 3078   // LDS row stride (f16): 1539 dw == 3 mod 8 -> <=3-way conflicts
#define LDS_BYTES (16 * WROW * 2 + 9216 * 4)
// bar layout: barA = bar[0..4095], barG = bar[4096..8191], pair flags after.
// Within a bar region: leaves at 64*i (i<16), root at 1024,
// fan-out generation lines at 1088 + 64*i (i<16)  [<=16 pollers per line].
#define BAR_U32 (8192 + 128 * 64)

// ---------------- P1: h0 = c0 = mean_p A[n][h][:]  ----------------
__global__ void k_h0(const float* __restrict__ A, float* __restrict__ c0,
                     f16* __restrict__ act_h0) {
  int idx = blockIdx.x * 256 + threadIdx.x;
  const float4* ap = (const float4*)(A + (size_t)idx * PP);
  float s = 0.f;
#pragma unroll
  for (int i = 0; i < PP / 4; ++i) { float4 v = ap[i]; s += v.x + v.y + v.z + v.w; }
  float m = s * (1.0f / PP);
  c0[idx] = m;
  act_h0[idx] = (f16)m;
}

// ---------------- P2: A[n][h][p] fp32 -> A2[n][p][h] fp16 ----------------
__global__ void k_At(const float* __restrict__ A, f16* __restrict__ A2) {
  __shared__ float tile[32][33];
  int p0 = blockIdx.x * 32, h0 = blockIdx.y * 32, n = blockIdx.z;
  for (int i = threadIdx.x; i < 1024; i += 256) {
    int r = i >> 5, c = i & 31;
    int p = p0 + c;
    float v = 0.f;
    if (p < PP) v = A[((size_t)n * HH + h0 + r) * PP + p];
    tile[r][c] = v;
  }
  __syncthreads();
  for (int i = threadIdx.x; i < 1024; i += 256) {
    int r = i >> 5, c = i & 31;
    int p = p0 + r;
    if (p < PP) A2[((size_t)n * PP + p) * HH + h0 + c] = (f16)tile[c][r];
  }
}

// ------ P3: Wt[j][k] fp16, col-major weights, k = [Wx;Wh;Wattn] ----------
__global__ void k_Wt(const float* __restrict__ Wx, const float* __restrict__ Wh,
                     const float* __restrict__ Wa, f16* __restrict__ Wt) {
  __shared__ float tile[32][33];
  int k0 = blockIdx.x * 32, j0 = blockIdx.y * 32;
  const float* src; int kb;
  if (k0 < 1024)      { src = Wx; kb = k0; }
  else if (k0 < 2048) { src = Wh; kb = k0 - 1024; }
  else                { src = Wa; kb = k0 - 2048; }
  for (int i = threadIdx.x; i < 1024; i += 256) {
    int r = i >> 5, c = i & 31;
    tile[r][c] = src[(size_t)(kb + r) * FOURH + j0 + c];
  }
  __syncthreads();
  for (int i = threadIdx.x; i < 1024; i += 256) {
    int r = i >> 5, c = i & 31;
    Wt[(size_t)(j0 + r) * K3 + k0 + c] = (f16)tile[c][r];
  }
}

// ---------------- P4: x fp32 -> fp16 ----------------
__global__ void k_xcvt(const float* __restrict__ x, f16* __restrict__ xh) {
  size_t i = (size_t)blockIdx.x * 256 + threadIdx.x;
  float4 v = ((const float4*)x)[i];
  f16x4 o; o[0] = (f16)v.x; o[1] = (f16)v.y; o[2] = (f16)v.z; o[3] = (f16)v.w;
  *(f16x4*)(xh + i * 4) = o;
}

// ------------- relaxed barrier primitives (no wbl2/inv on arrive) ------------
// Arrive: leaf RMW -> root RMW -> root winner FANS OUT the new generation to
// 16 separate cache lines. Wait: poll only your own fan line (<=16 pollers),
// eliminating the 256-poller serialization on a single uncached line that the
// round-0 model identified as ~10-15us per barrier release.
__device__ __forceinline__ void bar_arrive(unsigned* base, int bx) {
  asm volatile("s_waitcnt vmcnt(0)" ::: "memory");
  unsigned lv = __hip_atomic_fetch_add(base + (bx & 15) * 64, 1u,
                                       __ATOMIC_RELAXED, __HIP_MEMORY_SCOPE_AGENT);
  if ((lv & 15u) == 15u) {
    unsigned rv = __hip_atomic_fetch_add(base + 1024, 1u,
                                         __ATOMIC_RELAXED, __HIP_MEMORY_SCOPE_AGENT);
    if ((rv & 15u) == 15u) {
      unsigned g = (rv >> 4) + 1u;
#pragma unroll
      for (int i = 0; i < 16; ++i)
        __hip_atomic_store(base + 1088 + i * 64, g,
                           __ATOMIC_RELAXED, __HIP_MEMORY_SCOPE_AGENT);
    }
  }
}
__device__ __forceinline__ void bar_wait_acq(unsigned* base, int bx, unsigned target) {
  unsigned* line = base + 1088 + (bx & 15) * 64;
  while (__hip_atomic_load(line, __ATOMIC_RELAXED,
                           __HIP_MEMORY_SCOPE_AGENT) < target)
    __builtin_amdgcn_s_sleep(2);
  // acquire: single L2 invalidate so subsequent CACHED loads see coherent data
  (void)__hip_atomic_load(line, __ATOMIC_ACQUIRE, __HIP_MEMORY_SCOPE_AGENT);
}

__device__ __forceinline__ void coh_store_f16(f16* p, f16 v) {
  __hip_atomic_store((short*)p, __builtin_bit_cast(short, v),
                     __ATOMIC_RELAXED, __HIP_MEMORY_SCOPE_AGENT);
}
__device__ __forceinline__ void coh_store_f32(float* p, float v) {
  __hip_atomic_store(p, v, __ATOMIC_RELAXED, __HIP_MEMORY_SCOPE_AGENT);
}
__device__ __forceinline__ float coh_load_f32(const float* p) {
  return __hip_atomic_load(p, __ATOMIC_RELAXED, __HIP_MEMORY_SCOPE_AGENT);
}

// ---------------- persistent per-step kernel (cooperative) ----------------
// 256 blocks x 512 threads, 1 block/CU. A2 slice in registers; Wt slice in LDS.
// Per step: S -> pair-arrive -> G(x,h pre-compute) -> pair-wait -> A ->
//           global barA -> G(attn) + epilogue -> global barG.
__global__ __launch_bounds__(NTHR, 2) void k_steps(
    const f16* __restrict__ xh, const f16* __restrict__ A2,
    const f16* __restrict__ Wtg, const float* __restrict__ bias,
    const float* __restrict__ c0,
    f16* __restrict__ acth0, f16* __restrict__ acth1,
    f16* __restrict__ attnb, float* __restrict__ spart,
    float* __restrict__ out, unsigned* __restrict__ bar) {
  extern __shared__ char smem[];
  f16* wslab = (f16*)smem;                         // [16][WROW]
  float* uni   = (float*)(smem + 16 * WROW * 2);   // 9216 floats
  float* sc    = uni;                              // [208] own score partials
  float* wexp  = uni + 208;                        // [208] softmax weights
  float* srinv = uni + 416;
  float* red   = uni + 512;                        // [16][32][17] attn partials
  float* slabq = uni;                              // G: [4][128][18]

  int tid = threadIdx.x;
  int lane = tid & 63, wid = tid >> 6;
  int bx = blockIdx.x;
  unsigned* barA = bar;
  unsigned* barG = bar + 4096;
  unsigned* pflag = bar + 8192 + (bx >> 1) * 64;

  // ---- S/A geometry ----
  int n = bx >> 1, hhalf = bx & 1;
  int hsub = lane & 31;
  int pg = wid * 2 + (lane >> 5);

  // ---- A2 slice into registers (resident forever) ----
  f16x8 areg0[13], areg1[13];
  {
    const f16* Ab = A2 + ((size_t)n * PP) * HH + hhalf * 512 + hsub * 16;
#pragma unroll
    for (int i = 0; i < 13; ++i) {
      int p = pg + 16 * i; if (p >= PP) p = pg;
      areg0[i] = *(const f16x8*)(Ab + (size_t)p * HH);
      areg1[i] = *(const f16x8*)(Ab + (size_t)p * HH + 8);
    }
  }

  // ---- Wt slice into LDS (resident forever) ----
#pragma unroll 1
  for (int c = 0; c < 16; ++c) {
    if (tid < 384) {
      int j = (c >> 2) * 1024 + bx * 4 + (c & 3);
      f16x8 v = *(const f16x8*)(Wtg + (size_t)j * K3 + tid * 8);
      *(f16x8*)(wslab + c * WROW + tid * 8) = v;
    }
  }

  // ---- G geometry ----
  int l15 = lane & 15, quad = lane >> 4;
  int mhalf = wid & 1, kq = wid >> 1;
  int rowbase = mhalf * 64 + l15;
  const f16* wlp = wslab + l15 * WROW + quad * 8;
  int gn = tid >> 2, gh = tid & 3;
  int hs4 = bx * 4;
  float creg = c0[gn * HH + hs4 + gh];
  float b_i = bias[hs4 + gh], b_f = bias[1024 + hs4 + gh];
  float b_o = bias[2048 + hs4 + gh], b_g = bias[3072 + hs4 + gh];

  for (int t = 0; t < TT; ++t) {
    const f16* hcur = (t & 1) ? acth1 : acth0;
    f16* hnxt = (t & 1) ? acth0 : acth1;
    unsigned tgt = (unsigned)(t + 1);

    // ============ phase S: partial scores over this block's 512 h ============
    {
      const f16x8* hp = (const f16x8*)(hcur + (size_t)n * HH + hhalf * 512 + hsub * 16);
      f16x8 hv0 = hp[0], hv1 = hp[1];
      float hf[16];
#pragma unroll
      for (int e = 0; e < 8; ++e) { hf[e] = (float)hv0[e]; hf[8 + e] = (float)hv1[e]; }
#pragma unroll
      for (int i = 0; i < 13; ++i) {
        float s = 0.f;
#pragma unroll
        for (int e = 0; e < 8; ++e)
          s += hf[e] * (float)areg0[i][e] + hf[8 + e] * (float)areg1[i][e];
        s += __shfl_xor(s, 1, 64);
        s += __shfl_xor(s, 2, 64);
        s += __shfl_xor(s, 4, 64);
        s += __shfl_xor(s, 8, 64);
        s += __shfl_xor(s, 16, 64);
        int p = pg + 16 * i;
        if (hsub == 0 && p < PP) {
          sc[p] = s;
          coh_store_f32(spart + bx * 256 + p, s);
        }
      }
    }
    __syncthreads();                       // drains coherent spart stores
    if (tid == 0)
      __hip_atomic_fetch_add(pflag, 1u, __ATOMIC_RELAXED, __HIP_MEMORY_SCOPE_AGENT);

    // ============ phase Gxh: x-part + h-part of the gates GEMM (no attn dep) =
    f32x4 acc4[4];
#pragma unroll
    for (int i = 0; i < 4; ++i)
#pragma unroll
      for (int e = 0; e < 4; ++e) acc4[i][e] = 0.f;

    auto seg = [&](const f16* base, size_t rstride, int kgbase, int nks) {
#pragma unroll 4
      for (int ks = 0; ks < nks; ++ks) {
        const f16* ap = base + ks * 32 + quad * 8;
        f16x8 b = *(const f16x8*)(wlp + kgbase + ks * 32);
        f16x8 a0 = *(const f16x8*)(ap + (size_t)(rowbase)      * rstride);
        f16x8 a1 = *(const f16x8*)(ap + (size_t)(rowbase + 16) * rstride);
        f16x8 a2 = *(const f16x8*)(ap + (size_t)(rowbase + 32) * rstride);
        f16x8 a3 = *(const f16x8*)(ap + (size_t)(rowbase + 48) * rstride);
        acc4[0] = __builtin_amdgcn_mfma_f32_16x16x32_f16(a0, b, acc4[0], 0, 0, 0);
        acc4[1] = __builtin_amdgcn_mfma_f32_16x16x32_f16(a1, b, acc4[1], 0, 0, 0);
        acc4[2] = __builtin_amdgcn_mfma_f32_16x16x32_f16(a2, b, acc4[2], 0, 0, 0);
        acc4[3] = __builtin_amdgcn_mfma_f32_16x16x32_f16(a3, b, acc4[3], 0, 0, 0);
      }
    };
    {
      const f16* xrow = xh + (size_t)t * DD;
      if (kq == 0)      seg(xrow,        (size_t)TT * DD, 0,    16);
      else if (kq == 1) seg(xrow + 512,  (size_t)TT * DD, 512,  16);
      else if (kq == 2) seg(hcur,        HH,              1024, 16);
      else              seg(hcur + 512,  HH,              1536, 16);
    }

    // ============ pair-wait, then phase A (softmax + attn from registers) ====
    if (tid == 0) {
      while (__hip_atomic_load(pflag, __ATOMIC_RELAXED, __HIP_MEMORY_SCOPE_AGENT)
             < 2u * tgt)
        __builtin_amdgcn_s_sleep(2);
    }
    __syncthreads();
    {
      if (wid == 0) {
        const float* pp = spart + (bx ^ 1) * 256;
        float s0 = (sc[lane]       + coh_load_f32(pp + lane))       * 0.03125f;
        float s1 = (sc[64 + lane]  + coh_load_f32(pp + 64 + lane))  * 0.03125f;
        float s2 = (sc[128 + lane] + coh_load_f32(pp + 128 + lane)) * 0.03125f;
        float s3 = (lane < 4) ? (sc[192 + lane] + coh_load_f32(pp + 192 + lane)) * 0.03125f
                              : -1e30f;
        float mx = fmaxf(fmaxf(s0, s1), fmaxf(s2, s3));
#pragma unroll
        for (int off = 32; off > 0; off >>= 1) mx = fmaxf(mx, __shfl_xor(mx, off, 64));
        float e0 = __expf(s0 - mx), e1 = __expf(s1 - mx), e2 = __expf(s2 - mx);
        float e3 = (lane < 4) ? __expf(s3 - mx) : 0.f;
        float ssum = e0 + e1 + e2 + e3;
#pragma unroll
        for (int off = 32; off > 0; off >>= 1) ssum += __shfl_xor(ssum, off, 64);
        wexp[lane] = e0; wexp[64 + lane] = e1; wexp[128 + lane] = e2;
        if (lane < 4)  wexp[192 + lane] = e3;
        if (lane < 12) wexp[196 + lane] = 0.f;
        if (lane == 0) *srinv = 1.f / ssum;
      }
      __syncthreads();
      float acc[16];
#pragma unroll
      for (int e = 0; e < 16; ++e) acc[e] = 0.f;
#pragma unroll
      for (int i = 0; i < 13; ++i) {
        float wgt = wexp[pg + 16 * i];
#pragma unroll
        for (int e = 0; e < 8; ++e) {
          acc[e]     += wgt * (float)areg0[i][e];
          acc[8 + e] += wgt * (float)areg1[i][e];
        }
      }
#pragma unroll
      for (int e = 0; e < 16; ++e) red[pg * 544 + hsub * 17 + e] = acc[e];
      __syncthreads();
      float s = 0.f;
      int ra = (tid >> 4) * 17 + (tid & 15);
#pragma unroll
      for (int g = 0; g < 16; ++g) s += red[g * 544 + ra];
      coh_store_f16(attnb + (size_t)n * HH + hhalf * 512 + tid,
                    (f16)(s * (*srinv)));
    }
    __syncthreads();                       // drains coherent attnb stores
    if (tid == 0) { bar_arrive(barA, bx); bar_wait_acq(barA, bx, tgt); }
    __syncthreads();

    // ============ phase Gattn: attn-part of GEMM + LSTM epilogue =============
    seg(attnb + kq * 256, HH, 2048 + kq * 256, 8);

#pragma unroll
    for (int mt = 0; mt < 4; ++mt)
#pragma unroll
      for (int jr = 0; jr < 4; ++jr)
        slabq[kq * 2304 + (mhalf * 64 + mt * 16 + quad * 4 + jr) * 18 + l15] =
            acc4[mt][jr];
    __syncthreads();
    {
      float ai = b_i, af = b_f, ao = b_o, ag = b_g;
#pragma unroll
      for (int q = 0; q < 4; ++q) {
        const float* sl = slabq + q * 2304 + gn * 18;
        ai += sl[gh]; af += sl[4 + gh]; ao += sl[8 + gh]; ag += sl[12 + gh];
      }
      float ig = 1.f / (1.f + __expf(-ai));
      float fg = 1.f / (1.f + __expf(-af));
      float og = 1.f / (1.f + __expf(-ao));
      float gg = tanhf(ag);
      creg = fg * creg + ig * gg;
      float hn = og * tanhf(creg);
      __builtin_nontemporal_store(hn, &out[((size_t)gn * TT + t) * HH + hs4 + gh]);
      coh_store_f16(hnxt + gn * HH + hs4 + gh, (f16)hn);
    }
    __syncthreads();                       // drains coherent acth stores
    if (tid == 0) { bar_arrive(barG, bx); bar_wait_acq(barG, bx, tgt); }
    __syncthreads();
  }
}

extern "C" void kernel_launch(void* const* d_in, const int* in_sizes, int n_in,
                              void* d_out, int out_size, void* d_ws, size_t ws_size,
                              hipStream_t stream) {
  const float* x  = (const float*)d_in[0];
  const float* A  = (const float*)d_in[1];
  const float* Wx = (const float*)d_in[2];
  const float* Wh = (const float*)d_in[3];
  const float* Wa = (const float*)d_in[4];
  const float* b  = (const float*)d_in[5];
  float* out = (float*)d_out;

  char* ws = (char*)d_ws;
  f16* A2 = (f16*)ws;          ws += (size_t)NB * PP * HH * 2;
  f16* Wt = (f16*)ws;          ws += (size_t)FOURH * K3 * 2;
  f16* xh = (f16*)ws;          ws += (size_t)NB * TT * DD * 2;
  f16* acth0 = (f16*)ws;       ws += (size_t)NB * HH * 2;
  f16* acth1 = (f16*)ws;       ws += (size_t)NB * HH * 2;
  f16* attnb = (f16*)ws;       ws += (size_t)NB * HH * 2;
  float* c0 = (float*)ws;      ws += (size_t)NB * HH * 4;
  float* spart = (float*)ws;   ws += (size_t)NBLK * 256 * 4;
  unsigned* bar = (unsigned*)ws; ws += (size_t)BAR_U32 * 4;

  static int attr_set = 0;
  if (!attr_set) {
    hipFuncSetAttribute((const void*)k_steps,
                        hipFuncAttributeMaxDynamicSharedMemorySize, LDS_BYTES);
    attr_set = 1;
  }

  hipMemsetAsync(bar, 0, BAR_U32 * 4, stream);
  k_h0<<<512, 256, 0, stream>>>(A, c0, acth0);
  k_At<<<dim3(7, 32, NB), 256, 0, stream>>>(A, A2);
  k_Wt<<<dim3(96, 128), 256, 0, stream>>>(Wx, Wh, Wa, Wt);
  k_xcvt<<<32768, 256, 0, stream>>>(x, xh);

  void* args[] = { (void*)&xh, (void*)&A2, (void*)&Wt, (void*)&b, (void*)&c0,
                   (void*)&acth0, (void*)&acth1, (void*)&attnb, (void*)&spart,
                   (void*)&out, (void*)&bar };
  hipLaunchCooperativeKernel((const void*)k_steps, dim3(NBLK), dim3(NTHR),
                             args, LDS_BYTES, stream);
}